// Round 4
// baseline (286.824 us; speedup 1.0000x reference)
//
#include <hip/hip_runtime.h>

typedef __bf16 bf16;
typedef __bf16 bf16x8 __attribute__((ext_vector_type(8)));
typedef float f32x4 __attribute__((ext_vector_type(4)));

#define MFMA16(a, b, c) __builtin_amdgcn_mfma_f32_16x16x32_bf16((a), (b), (c), 0, 0, 0)

constexpr int B_ = 2, S_ = 2048, D_ = 1024, H_ = 16, DK_ = 64;

// Stage 16 contiguous elements (f32 -> bf16 convert, or bf16 passthrough) into LDS.
template <typename T>
__device__ __forceinline__ void stage16(bf16* dst, const T* src)
{
  if constexpr (sizeof(T) == 4) {
    const float4 a = ((const float4*)src)[0];
    const float4 b = ((const float4*)src)[1];
    const float4 c = ((const float4*)src)[2];
    const float4 d = ((const float4*)src)[3];
    bf16x8 lo = {(bf16)a.x, (bf16)a.y, (bf16)a.z, (bf16)a.w,
                 (bf16)b.x, (bf16)b.y, (bf16)b.z, (bf16)b.w};
    bf16x8 hi = {(bf16)c.x, (bf16)c.y, (bf16)c.z, (bf16)c.w,
                 (bf16)d.x, (bf16)d.y, (bf16)d.z, (bf16)d.w};
    *(bf16x8*)dst = lo;
    *(bf16x8*)(dst + 8) = hi;
  } else {
    *(bf16x8*)dst = *(const bf16x8*)src;
    *(bf16x8*)(dst + 8) = *(const bf16x8*)(src + 8);
  }
}

// ---------------------------------------------------------------------------
// GEMM: Y = X @ W^T.  X: MxK row-major (f32 or bf16), W: NxK row-major f32.
// perm==0: Y[m*N + n]                      (row-major MxN, dtype TY)
// perm==1: Y[((b*H + h)*S + s)*DK + d]     (B,H,S,DK) with m=b*S+s, n=h*DK+d
// ---------------------------------------------------------------------------
template <typename TX, typename TY>
__global__ __launch_bounds__(256) void gemm_xwt(
    const TX* __restrict__ X, const float* __restrict__ W, TY* __restrict__ Y,
    int M, int N, int K, int perm)
{
  __shared__ __align__(16) bf16 Xs[64][72];
  __shared__ __align__(16) bf16 Ws[64][72];
  const int t = threadIdx.x;
  const int l = t & 63, w = t >> 6;
  const int wm = w >> 1, wn = w & 1;
  const int m0 = blockIdx.x * 64, n0 = blockIdx.y * 64;
  const int sr = t >> 2, scg = (t & 3) * 16;

  f32x4 acc[2][2] = {};

  for (int k0 = 0; k0 < K; k0 += 64) {
    stage16(&Xs[sr][scg], X + (size_t)(m0 + sr) * K + k0 + scg);
    stage16(&Ws[sr][scg], W + (size_t)(n0 + sr) * K + k0 + scg);
    __syncthreads();
#pragma unroll
    for (int kk = 0; kk < 2; ++kk) {
      bf16x8 a0 = *(const bf16x8*)&Xs[wm * 32 + (l & 15)][kk * 32 + (l >> 4) * 8];
      bf16x8 a1 = *(const bf16x8*)&Xs[wm * 32 + 16 + (l & 15)][kk * 32 + (l >> 4) * 8];
      bf16x8 b0 = *(const bf16x8*)&Ws[wn * 32 + (l & 15)][kk * 32 + (l >> 4) * 8];
      bf16x8 b1 = *(const bf16x8*)&Ws[wn * 32 + 16 + (l & 15)][kk * 32 + (l >> 4) * 8];
      acc[0][0] = MFMA16(a0, b0, acc[0][0]);
      acc[0][1] = MFMA16(a0, b1, acc[0][1]);
      acc[1][0] = MFMA16(a1, b0, acc[1][0]);
      acc[1][1] = MFMA16(a1, b1, acc[1][1]);
    }
    __syncthreads();
  }

#pragma unroll
  for (int mi = 0; mi < 2; ++mi)
#pragma unroll
    for (int ni = 0; ni < 2; ++ni)
#pragma unroll
      for (int j = 0; j < 4; ++j) {
        int m = m0 + wm * 32 + mi * 16 + (l >> 4) * 4 + j;
        int n = n0 + wn * 32 + ni * 16 + (l & 15);
        TY v = (TY)acc[mi][ni][j];
        if (perm == 0) {
          Y[(size_t)m * N + n] = v;
        } else {
          int b = m >> 11, s = m & (S_ - 1), h = n >> 6, d = n & (DK_ - 1);
          Y[(((size_t)(b * H_ + h)) * S_ + s) * DK_ + d] = v;
        }
      }
}

// ---------------------------------------------------------------------------
// RoPE in-place on Q and K (layout B,H,S,DK). One thread per rotation pair.
// ---------------------------------------------------------------------------
__global__ __launch_bounds__(256) void rope_k(
    bf16* __restrict__ Q, bf16* __restrict__ K, const int* __restrict__ pos, int npairs)
{
  int i = blockIdx.x * blockDim.x + threadIdx.x;
  bf16* buf = (i < npairs) ? Q : K;
  int idx = (i < npairs) ? i : i - npairs;
  int kp = idx & 31;                 // pair index 0..31
  int s = (idx >> 5) & (S_ - 1);     // seq position
  int bh = idx >> 16;                // b*H + h
  int p = pos[s];
  float inv = powf(10000.0f, -(float)kp / 32.0f);
  float ang = (float)p * inv;
  float sn, cs;
  sincosf(ang, &sn, &cs);
  size_t off = ((size_t)bh * S_ + s) * DK_ + kp * 2;
  float x0 = (float)buf[off], x1 = (float)buf[off + 1];
  buf[off] = (bf16)(x0 * cs - x1 * sn);
  buf[off + 1] = (bf16)(x0 * sn + x1 * cs);
}

// ---------------------------------------------------------------------------
// Causal flash attention. One block per (b, h, 64-row q-tile); 4 waves,
// each wave owns 16 q-rows. K row-major + V transposed in LDS.
// Output O in (B,S,H*DK) layout for the final projection GEMM.
// ---------------------------------------------------------------------------
__global__ __launch_bounds__(256) void attn_k(
    const bf16* __restrict__ Q, const bf16* __restrict__ K, const bf16* __restrict__ V,
    bf16* __restrict__ O)
{
  __shared__ __align__(16) bf16 Qs[64][72];
  __shared__ __align__(16) bf16 Ks[64][72];
  __shared__ __align__(16) bf16 Vt[64][72];   // [d][kv]
  __shared__ __align__(16) bf16 Ps[4][16][72];

  const int t = threadIdx.x, l = t & 63, w = t >> 6;
  const int qt = blockIdx.x & 31;
  const int bh = blockIdx.x >> 5;
  const int b = bh >> 4, h = bh & 15;
  const size_t base = (size_t)bh * S_ * DK_;
  const int sr = t >> 2, scg = (t & 3) * 16;
  const int q0 = qt * 64;

  // stage Q, pre-scaled by 1/sqrt(DK)=0.125 (exact in bf16)
  {
    const bf16* pq = Q + base + (size_t)(q0 + sr) * DK_ + scg;
    bf16x8 v0 = *(const bf16x8*)pq;
    bf16x8 v1 = *(const bf16x8*)(pq + 8);
#pragma unroll
    for (int i = 0; i < 8; ++i) {
      Qs[sr][scg + i] = (bf16)((float)v0[i] * 0.125f);
      Qs[sr][scg + 8 + i] = (bf16)((float)v1[i] * 0.125f);
    }
  }
  __syncthreads();

  bf16x8 aq0 = *(const bf16x8*)&Qs[w * 16 + (l & 15)][(l >> 4) * 8];
  bf16x8 aq1 = *(const bf16x8*)&Qs[w * 16 + (l & 15)][32 + (l >> 4) * 8];

  f32x4 acc[4] = {};
  float mrun[4], lsum[4];
#pragma unroll
  for (int j = 0; j < 4; ++j) { mrun[j] = -1e30f; lsum[j] = 0.f; }

  for (int tk = 0; tk <= qt; ++tk) {
    __syncthreads();  // protect Ks/Vt reuse across iterations
    const int kv0 = tk * 64;
    {
      const bf16* pk = K + base + (size_t)(kv0 + sr) * DK_ + scg;
      *(bf16x8*)&Ks[sr][scg] = *(const bf16x8*)pk;
      *(bf16x8*)&Ks[sr][scg + 8] = *(const bf16x8*)(pk + 8);
      const bf16* pv = V + base + (size_t)(kv0 + sr) * DK_ + scg;
      bf16x8 v0 = *(const bf16x8*)pv;
      bf16x8 v1 = *(const bf16x8*)(pv + 8);
#pragma unroll
      for (int i = 0; i < 8; ++i) {
        Vt[scg + i][sr] = v0[i];
        Vt[scg + 8 + i][sr] = v1[i];
      }
    }
    __syncthreads();

    // S = Q K^T  (16 q-rows x 64 kv-cols per wave)
    f32x4 sc4[4];
#pragma unroll
    for (int nf = 0; nf < 4; ++nf) {
      bf16x8 b0 = *(const bf16x8*)&Ks[nf * 16 + (l & 15)][(l >> 4) * 8];
      bf16x8 b1 = *(const bf16x8*)&Ks[nf * 16 + (l & 15)][32 + (l >> 4) * 8];
      f32x4 s = {};
      s = MFMA16(aq0, b0, s);
      s = MFMA16(aq1, b1, s);
      sc4[nf] = s;
    }

    if (tk == qt) {  // diagonal tile: causal mask
#pragma unroll
      for (int nf = 0; nf < 4; ++nf)
#pragma unroll
        for (int j = 0; j < 4; ++j) {
          int kvl = nf * 16 + (l & 15);
          int ql = w * 16 + (l >> 4) * 4 + j;
          if (kvl > ql) sc4[nf][j] = -1e30f;
        }
    }

    // online softmax (row r = (l>>4)*4+j lives in the 16 lanes sharing l>>4)
    float pm[4];
#pragma unroll
    for (int j = 0; j < 4; ++j)
      pm[j] = fmaxf(fmaxf(sc4[0][j], sc4[1][j]), fmaxf(sc4[2][j], sc4[3][j]));
#pragma unroll
    for (int m = 1; m <= 8; m <<= 1)
#pragma unroll
      for (int j = 0; j < 4; ++j)
        pm[j] = fmaxf(pm[j], __shfl_xor(pm[j], m, 64));

    float alpha[4];
#pragma unroll
    for (int j = 0; j < 4; ++j) {
      float nm = fmaxf(mrun[j], pm[j]);
      alpha[j] = __expf(mrun[j] - nm);
      mrun[j] = nm;
    }

    float rs[4] = {0.f, 0.f, 0.f, 0.f};
#pragma unroll
    for (int nf = 0; nf < 4; ++nf)
#pragma unroll
      for (int j = 0; j < 4; ++j) {
        float p = __expf(sc4[nf][j] - mrun[j]);
        rs[j] += p;
        Ps[w][(l >> 4) * 4 + j][nf * 16 + (l & 15)] = (bf16)p;
      }
#pragma unroll
    for (int m = 1; m <= 8; m <<= 1)
#pragma unroll
      for (int j = 0; j < 4; ++j)
        rs[j] += __shfl_xor(rs[j], m, 64);
#pragma unroll
    for (int j = 0; j < 4; ++j) lsum[j] = lsum[j] * alpha[j] + rs[j];
#pragma unroll
    for (int nf = 0; nf < 4; ++nf)
#pragma unroll
      for (int j = 0; j < 4; ++j)
        acc[nf][j] *= alpha[j];

    // wave-local P roundtrip: wait for our ds_writes before frag reads
    asm volatile("s_waitcnt lgkmcnt(0)" ::: "memory");

    // O += P V
#pragma unroll
    for (int kk = 0; kk < 2; ++kk) {
      bf16x8 ap = *(const bf16x8*)&Ps[w][l & 15][kk * 32 + (l >> 4) * 8];
#pragma unroll
      for (int nf = 0; nf < 4; ++nf) {
        bf16x8 bv = *(const bf16x8*)&Vt[nf * 16 + (l & 15)][kk * 32 + (l >> 4) * 8];
        acc[nf] = MFMA16(ap, bv, acc[nf]);
      }
    }
  }

  // epilogue: normalize and write O in (B,S,H*DK)
#pragma unroll
  for (int nf = 0; nf < 4; ++nf)
#pragma unroll
    for (int j = 0; j < 4; ++j) {
      int q = q0 + w * 16 + (l >> 4) * 4 + j;
      int d = nf * 16 + (l & 15);
      float v = acc[nf][j] / lsum[j];
      O[((size_t)(b * S_ + q) * H_ + h) * DK_ + d] = (bf16)v;
    }
}

// ---------------------------------------------------------------------------
extern "C" void kernel_launch(void* const* d_in, const int* in_sizes, int n_in,
                              void* d_out, int out_size, void* d_ws, size_t ws_size,
                              hipStream_t stream)
{
  // Dtype evidence (rounds 0-3): all float inputs are f32 on device (reference
  // dtypes are f32; npz size matches all-f32; bf16-reading x NaNs). Output is
  // f32 (stub run read zeros as f32; bf16 writes decoded as garbage floats).
  const float* x = (const float*)d_in[0];
  const float* Wq = (const float*)d_in[1];
  const float* Wk = (const float*)d_in[2];
  const float* Wv = (const float*)d_in[3];
  const float* Wo = (const float*)d_in[4];
  const int* pos = (const int*)d_in[5];

  bf16* ws = (bf16*)d_ws;
  const size_t NE = (size_t)B_ * H_ * S_ * DK_;  // 4,194,304
  bf16* Qb = ws;
  bf16* Kb = ws + NE;
  bf16* Vb = ws + 2 * NE;
  bf16* Ob = ws + 3 * NE;

  dim3 blk(256);
  dim3 g(64, 16);  // M/64 x N/64 for M=4096, N=1024

  // QKV projections (+ scatter into B,H,S,DK)
  hipLaunchKernelGGL((gemm_xwt<float, bf16>), g, blk, 0, stream, x, Wq, Qb, 4096, 1024, 1024, 1);
  hipLaunchKernelGGL((gemm_xwt<float, bf16>), g, blk, 0, stream, x, Wk, Kb, 4096, 1024, 1024, 1);
  hipLaunchKernelGGL((gemm_xwt<float, bf16>), g, blk, 0, stream, x, Wv, Vb, 4096, 1024, 1024, 1);

  // RoPE on Q and K
  int npairs = B_ * H_ * S_ * (DK_ / 2);  // 2,097,152
  hipLaunchKernelGGL(rope_k, dim3((2 * npairs) / 256), blk, 0, stream, Qb, Kb, pos, npairs);

  // causal flash attention -> O in (B,S,H*DK)
  hipLaunchKernelGGL(attn_k, dim3(B_ * H_ * (S_ / 64)), blk, 0, stream, Qb, Kb, Vb, Ob);

  // output projection -> d_out (f32)
  hipLaunchKernelGGL((gemm_xwt<bf16, float>), g, blk, 0, stream, Ob, Wo, (float*)d_out, 4096, 1024, 1024, 0);
}

// Round 5
// 215.511 us; speedup vs baseline: 1.3309x; 1.3309x over previous
//
#include <hip/hip_runtime.h>

typedef __bf16 bf16;
typedef __bf16 bf16x4 __attribute__((ext_vector_type(4)));
typedef __bf16 bf16x8 __attribute__((ext_vector_type(8)));
typedef float f32x4 __attribute__((ext_vector_type(4)));

#define MFMA16(a, b, c) __builtin_amdgcn_mfma_f32_16x16x32_bf16((a), (b), (c), 0, 0, 0)

constexpr int B_ = 2, S_ = 2048, D_ = 1024, H_ = 16, DK_ = 64;

// async global->LDS, 16B per lane. LDS dest must be wave-uniform base (+lane*16 implicit).
__device__ __forceinline__ void gload16(const bf16* g, bf16* l)
{
  __builtin_amdgcn_global_load_lds(
      (const __attribute__((address_space(1))) uint32_t*)g,
      (__attribute__((address_space(3))) uint32_t*)l, 16, 0, 0);
}

// ---------------------------------------------------------------------------
// Convert f32 inputs (x + 4 weights) to bf16 workspace images.
// ws layout (elements): xb[4194304] | Wqb|Wkb|Wvb|Wob [1048576 each]
// ---------------------------------------------------------------------------
__global__ __launch_bounds__(256) void cvt_k(
    const float* __restrict__ x, const float* __restrict__ Wq, const float* __restrict__ Wk,
    const float* __restrict__ Wv, const float* __restrict__ Wo, bf16* __restrict__ ws)
{
  size_t f = ((size_t)blockIdx.x * 256 + threadIdx.x) * 4;
  const float* src;
  bf16* dst;
  size_t off;
  if (f < 4194304) {
    src = x; dst = ws; off = f;
  } else {
    size_t g = f - 4194304;
    int wsel = (int)(g >> 20);
    off = g & 1048575;
    src = wsel == 0 ? Wq : wsel == 1 ? Wk : wsel == 2 ? Wv : Wo;
    dst = ws + 4194304 + ((size_t)wsel << 20);
  }
  float4 v = *(const float4*)(src + off);
  bf16x4 o = {(bf16)v.x, (bf16)v.y, (bf16)v.z, (bf16)v.w};
  *(bf16x4*)(dst + off) = o;
}

// ---------------------------------------------------------------------------
// 128x128-tile GEMM, BK=64, 4 waves (2x2), 64x64 acc per wave (m97 structure).
// A: MxK bf16 row-major. W: NxK bf16 row-major (z selects among 3).
// LDS: linear dest for global_load_lds; logical [row][col8] stored at slot
// row*8 + (col8 ^ (row&7))  (XOR swizzle via pre-swizzled global source).
// PERM==0: Y[m*1024+n] (f32). PERM==1: scatter to (B,H,S,DK) bf16, *scale0 for z==0.
// ---------------------------------------------------------------------------
template <typename TY, int PERM>
__global__ __launch_bounds__(256) void gemm_k(
    const bf16* __restrict__ A,
    const bf16* __restrict__ W0, const bf16* __restrict__ W1, const bf16* __restrict__ W2,
    TY* __restrict__ Y0, TY* __restrict__ Y1, TY* __restrict__ Y2,
    int Kdim, float scale0)
{
  __shared__ __align__(16) bf16 As[128 * 64];
  __shared__ __align__(16) bf16 Bs[128 * 64];
  const int t = threadIdx.x, l = t & 63, w = t >> 6;
  const int wm = w >> 1, wn = w & 1;
  const int m0 = blockIdx.x * 128, n0 = blockIdx.y * 128;
  const int z = blockIdx.z;
  const bf16* W = z == 0 ? W0 : z == 1 ? W1 : W2;
  TY* Y = z == 0 ? Y0 : z == 1 ? Y1 : Y2;
  const float scale = (PERM == 1 && z == 0) ? scale0 : 1.0f;

  f32x4 acc[4][4] = {};

  for (int k0 = 0; k0 < Kdim; k0 += 64) {
    __syncthreads();  // previous iteration's LDS reads complete
#pragma unroll
    for (int j = 0; j < 4; ++j) {
      int slot = j * 256 + t;
      int row = slot >> 3, c8 = slot & 7;
      int csw = (c8 ^ (row & 7)) << 3;
      gload16(A + (size_t)(m0 + row) * Kdim + k0 + csw, &As[(j * 256 + w * 64) * 8]);
      gload16(W + (size_t)(n0 + row) * Kdim + k0 + csw, &Bs[(j * 256 + w * 64) * 8]);
    }
    asm volatile("s_waitcnt vmcnt(0)" ::: "memory");
    __syncthreads();
#pragma unroll
    for (int kk = 0; kk < 2; ++kk) {
      bf16x8 af[4], bfr[4];
#pragma unroll
      for (int i = 0; i < 4; ++i) {
        int Ra = wm * 64 + i * 16 + (l & 15);
        int Rb = wn * 64 + i * 16 + (l & 15);
        int c = kk * 4 + (l >> 4);
        af[i] = *(const bf16x8*)&As[Ra * 64 + ((c ^ (Ra & 7)) << 3)];
        bfr[i] = *(const bf16x8*)&Bs[Rb * 64 + ((c ^ (Rb & 7)) << 3)];
      }
#pragma unroll
      for (int mi = 0; mi < 4; ++mi)
#pragma unroll
        for (int ni = 0; ni < 4; ++ni)
          acc[mi][ni] = MFMA16(af[mi], bfr[ni], acc[mi][ni]);
    }
  }

#pragma unroll
  for (int mi = 0; mi < 4; ++mi)
#pragma unroll
    for (int ni = 0; ni < 4; ++ni)
#pragma unroll
      for (int j = 0; j < 4; ++j) {
        int m = m0 + wm * 64 + mi * 16 + (l >> 4) * 4 + j;
        int n = n0 + wn * 64 + ni * 16 + (l & 15);
        float v = acc[mi][ni][j] * scale;
        if (PERM == 0) {
          Y[(size_t)m * 1024 + n] = (TY)v;
        } else {
          int b = m >> 11, s = m & (S_ - 1), h = n >> 6, d = n & (DK_ - 1);
          Y[(((size_t)(b * H_ + h)) * S_ + s) * DK_ + d] = (TY)v;
        }
      }
}

// ---------------------------------------------------------------------------
// RoPE in-place on Q and K (layout B,H,S,DK). One thread per rotation pair.
// ---------------------------------------------------------------------------
__global__ __launch_bounds__(256) void rope_k(
    bf16* __restrict__ Q, bf16* __restrict__ K, const int* __restrict__ pos, int npairs)
{
  int i = blockIdx.x * blockDim.x + threadIdx.x;
  bf16* buf = (i < npairs) ? Q : K;
  int idx = (i < npairs) ? i : i - npairs;
  int kp = idx & 31;
  int s = (idx >> 5) & (S_ - 1);
  int bh = idx >> 16;
  int p = pos[s];
  float inv = powf(10000.0f, -(float)kp / 32.0f);
  float ang = (float)p * inv;
  float sn, cs;
  sincosf(ang, &sn, &cs);
  size_t off = ((size_t)bh * S_ + s) * DK_ + kp * 2;
  float x0 = (float)buf[off], x1 = (float)buf[off + 1];
  buf[off] = (bf16)(x0 * cs - x1 * sn);
  buf[off + 1] = (bf16)(x0 * sn + x1 * cs);
}

// ---------------------------------------------------------------------------
// Causal flash attention, 4 waves x 16 q-rows, KVBLK=64, double-buffered K/V.
// K staged via swizzled global_load_lds; V staged kv-major (conflict-free
// transpose writes); Q fragments direct from global (pre-scaled by 0.125).
// ---------------------------------------------------------------------------
__global__ __launch_bounds__(256) void attn_k(
    const bf16* __restrict__ Q, const bf16* __restrict__ K, const bf16* __restrict__ V,
    bf16* __restrict__ O)
{
  __shared__ __align__(16) bf16 Klds[2][64 * 64];
  __shared__ __align__(16) bf16 Vt[2][64][72];  // [d][kv]
  __shared__ __align__(16) bf16 Ps[4][16][72];

  const int t = threadIdx.x, l = t & 63, w = t >> 6;
  const int qt = blockIdx.x & 31;
  const int bh = blockIdx.x >> 5;
  const int b = bh >> 4, h = bh & 15;
  const size_t base = (size_t)bh * S_ * DK_;
  const int q0 = qt * 64;

  // Q fragments direct from global (scaled by 1/8 in the projection epilogue)
  const bf16* pq = Q + base + (size_t)(q0 + w * 16 + (l & 15)) * 64 + ((l >> 4) * 8);
  bf16x8 aq0 = *(const bf16x8*)pq;
  bf16x8 aq1 = *(const bf16x8*)(pq + 32);

  // prologue: stage K[0] (swizzled gload_lds) + V[0] (regs -> transposed LDS)
  {
#pragma unroll
    for (int j = 0; j < 2; ++j) {
      int slot = j * 256 + t, row = slot >> 3, c8 = slot & 7;
      gload16(K + base + (size_t)row * 64 + ((c8 ^ (row & 7)) << 3),
              &Klds[0][(j * 256 + w * 64) * 8]);
    }
    const bf16* pv = V + base + (size_t)l * 64 + w * 16;
    bf16x8 v0 = *(const bf16x8*)pv, v1 = *(const bf16x8*)(pv + 8);
    asm volatile("s_waitcnt vmcnt(0)" ::: "memory");
#pragma unroll
    for (int i = 0; i < 8; ++i) {
      Vt[0][w * 16 + i][l] = v0[i];
      Vt[0][w * 16 + 8 + i][l] = v1[i];
    }
  }
  __syncthreads();

  f32x4 acc[4] = {};
  float mrun[4], lsum[4];
#pragma unroll
  for (int j = 0; j < 4; ++j) { mrun[j] = -1e30f; lsum[j] = 0.f; }

  int cur = 0;
  for (int tk = 0; tk <= qt; ++tk) {
    const int nxt = cur ^ 1;
    const bool hasn = tk < qt;
    bf16x8 v0, v1;
    if (hasn) {  // issue next tile's loads before compute (2-phase pipeline)
      const int kv0n = (tk + 1) * 64;
#pragma unroll
      for (int j = 0; j < 2; ++j) {
        int slot = j * 256 + t, row = slot >> 3, c8 = slot & 7;
        gload16(K + base + (size_t)(kv0n + row) * 64 + ((c8 ^ (row & 7)) << 3),
                &Klds[nxt][(j * 256 + w * 64) * 8]);
      }
      const bf16* pv = V + base + (size_t)(kv0n + l) * 64 + w * 16;
      v0 = *(const bf16x8*)pv;
      v1 = *(const bf16x8*)(pv + 8);
    }

    // S = Q K^T (16 q-rows x 64 kv per wave), swizzled K reads
    f32x4 sc4[4];
#pragma unroll
    for (int nf = 0; nf < 4; ++nf) {
      int R = nf * 16 + (l & 15);
      int c0 = l >> 4;
      bf16x8 b0 = *(const bf16x8*)&Klds[cur][R * 64 + ((c0 ^ (R & 7)) << 3)];
      bf16x8 b1 = *(const bf16x8*)&Klds[cur][R * 64 + (((4 + c0) ^ (R & 7)) << 3)];
      f32x4 s = {};
      s = MFMA16(aq0, b0, s);
      s = MFMA16(aq1, b1, s);
      sc4[nf] = s;
    }

    if (tk == qt) {  // causal mask on diagonal tile
#pragma unroll
      for (int nf = 0; nf < 4; ++nf)
#pragma unroll
        for (int j = 0; j < 4; ++j) {
          int kvl = nf * 16 + (l & 15);
          int ql = w * 16 + (l >> 4) * 4 + j;
          if (kvl > ql) sc4[nf][j] = -1e30f;
        }
    }

    // online softmax (row r=(l>>4)*4+j lives in 16 lanes sharing l>>4)
    float pm[4];
#pragma unroll
    for (int j = 0; j < 4; ++j)
      pm[j] = fmaxf(fmaxf(sc4[0][j], sc4[1][j]), fmaxf(sc4[2][j], sc4[3][j]));
#pragma unroll
    for (int m = 1; m <= 8; m <<= 1)
#pragma unroll
      for (int j = 0; j < 4; ++j)
        pm[j] = fmaxf(pm[j], __shfl_xor(pm[j], m, 64));

    float alpha[4];
#pragma unroll
    for (int j = 0; j < 4; ++j) {
      float nm = fmaxf(mrun[j], pm[j]);
      alpha[j] = __expf(mrun[j] - nm);
      mrun[j] = nm;
    }

    float rs[4] = {0.f, 0.f, 0.f, 0.f};
#pragma unroll
    for (int nf = 0; nf < 4; ++nf)
#pragma unroll
      for (int j = 0; j < 4; ++j) {
        float p = __expf(sc4[nf][j] - mrun[j]);
        rs[j] += p;
        Ps[w][(l >> 4) * 4 + j][nf * 16 + (l & 15)] = (bf16)p;
      }
#pragma unroll
    for (int m = 1; m <= 8; m <<= 1)
#pragma unroll
      for (int j = 0; j < 4; ++j)
        rs[j] += __shfl_xor(rs[j], m, 64);
#pragma unroll
    for (int j = 0; j < 4; ++j) lsum[j] = lsum[j] * alpha[j] + rs[j];
#pragma unroll
    for (int nf = 0; nf < 4; ++nf)
#pragma unroll
      for (int j = 0; j < 4; ++j)
        acc[nf][j] *= alpha[j];

    // wave-local P roundtrip: our ds_writes must land before frag reads
    asm volatile("s_waitcnt lgkmcnt(0)" ::: "memory");

    // O += P V
#pragma unroll
    for (int kk = 0; kk < 2; ++kk) {
      bf16x8 ap = *(const bf16x8*)&Ps[w][l & 15][kk * 32 + (l >> 4) * 8];
#pragma unroll
      for (int nf = 0; nf < 4; ++nf) {
        bf16x8 bv = *(const bf16x8*)&Vt[cur][nf * 16 + (l & 15)][kk * 32 + (l >> 4) * 8];
        acc[nf] = MFMA16(ap, bv, acc[nf]);
      }
    }

    if (hasn) {  // land next V into the other buffer (conflict-free writes)
      asm volatile("s_waitcnt vmcnt(0)" ::: "memory");
#pragma unroll
      for (int i = 0; i < 8; ++i) {
        Vt[nxt][w * 16 + i][l] = v0[i];
        Vt[nxt][w * 16 + 8 + i][l] = v1[i];
      }
    }
    __syncthreads();
    cur = nxt;
  }

  // epilogue: normalize, write O in (B,S,H*DK)
#pragma unroll
  for (int nf = 0; nf < 4; ++nf)
#pragma unroll
    for (int j = 0; j < 4; ++j) {
      int q = q0 + w * 16 + (l >> 4) * 4 + j;
      int d = nf * 16 + (l & 15);
      float v = acc[nf][j] / lsum[j];
      O[((size_t)(b * S_ + q) * H_ + h) * DK_ + d] = (bf16)v;
    }
}

// ---------------------------------------------------------------------------
extern "C" void kernel_launch(void* const* d_in, const int* in_sizes, int n_in,
                              void* d_out, int out_size, void* d_ws, size_t ws_size,
                              hipStream_t stream)
{
  const float* x = (const float*)d_in[0];
  const float* Wq = (const float*)d_in[1];
  const float* Wk = (const float*)d_in[2];
  const float* Wv = (const float*)d_in[3];
  const float* Wo = (const float*)d_in[4];
  const int* pos = (const int*)d_in[5];

  bf16* ws = (bf16*)d_ws;
  const size_t NE = (size_t)B_ * H_ * S_ * DK_;  // 4,194,304
  bf16* xb = ws;                                 // also reused as Ob after QKV
  bf16* Wqb = ws + NE;
  bf16* Wkb = Wqb + 1048576;
  bf16* Wvb = Wkb + 1048576;
  bf16* Wob = Wvb + 1048576;
  bf16* Qb = Wob + 1048576;
  bf16* Kb = Qb + NE;
  bf16* Vb = Kb + NE;
  bf16* Ob = xb;  // x dead after QKV projections

  dim3 blk(256);

  // 1) convert inputs to bf16 images
  hipLaunchKernelGGL(cvt_k, dim3(8192), blk, 0, stream, x, Wq, Wk, Wv, Wo, ws);

  // 2) fused QKV projection (z=0:Q scaled 1/8, z=1:K, z=2:V), scatter to (B,H,S,DK)
  hipLaunchKernelGGL((gemm_k<bf16, 1>), dim3(32, 8, 3), blk, 0, stream,
                     xb, Wqb, Wkb, Wvb, Qb, Kb, Vb, 1024, 0.125f);

  // 3) RoPE on Q and K
  int npairs = B_ * H_ * S_ * (DK_ / 2);
  hipLaunchKernelGGL(rope_k, dim3((2 * npairs) / 256), blk, 0, stream, Qb, Kb, pos, npairs);

  // 4) causal flash attention -> Ob (B,S,H*DK)
  hipLaunchKernelGGL(attn_k, dim3(B_ * H_ * (S_ / 64)), blk, 0, stream, Qb, Kb, Vb, Ob);

  // 5) output projection -> d_out (f32)
  hipLaunchKernelGGL((gemm_k<float, 0>), dim3(32, 8, 1), blk, 0, stream,
                     Ob, Wob, Wob, Wob, (float*)d_out, (float*)d_out, (float*)d_out,
                     1024, 1.0f);
}

// Round 6
// 162.108 us; speedup vs baseline: 1.7693x; 1.3294x over previous
//
#include <hip/hip_runtime.h>

typedef __bf16 bf16;
typedef __bf16 bf16x4 __attribute__((ext_vector_type(4)));
typedef __bf16 bf16x8 __attribute__((ext_vector_type(8)));
typedef float f32x4 __attribute__((ext_vector_type(4)));

#define MFMA16(a, b, c) __builtin_amdgcn_mfma_f32_16x16x32_bf16((a), (b), (c), 0, 0, 0)

constexpr int B_ = 2, S_ = 2048, D_ = 1024, H_ = 16, DK_ = 64;

// async global->LDS, 16B per lane. LDS dest must be wave-uniform base (+lane*16 implicit).
__device__ __forceinline__ void gload16(const bf16* g, bf16* l)
{
  __builtin_amdgcn_global_load_lds(
      (const __attribute__((address_space(1))) uint32_t*)g,
      (__attribute__((address_space(3))) uint32_t*)l, 16, 0, 0);
}

// ---------------------------------------------------------------------------
// Convert f32 inputs (x + 4 weights) to bf16 workspace images.
// ---------------------------------------------------------------------------
__global__ __launch_bounds__(256) void cvt_k(
    const float* __restrict__ x, const float* __restrict__ Wq, const float* __restrict__ Wk,
    const float* __restrict__ Wv, const float* __restrict__ Wo, bf16* __restrict__ ws)
{
  size_t f = ((size_t)blockIdx.x * 256 + threadIdx.x) * 4;
  const float* src;
  bf16* dst;
  size_t off;
  if (f < 4194304) {
    src = x; dst = ws; off = f;
  } else {
    size_t g = f - 4194304;
    int wsel = (int)(g >> 20);
    off = g & 1048575;
    src = wsel == 0 ? Wq : wsel == 1 ? Wk : wsel == 2 ? Wv : Wo;
    dst = ws + 4194304 + ((size_t)wsel << 20);
  }
  float4 v = *(const float4*)(src + off);
  bf16x4 o = {(bf16)v.x, (bf16)v.y, (bf16)v.z, (bf16)v.w};
  *(bf16x4*)(dst + off) = o;
}

// ---------------------------------------------------------------------------
// 128x128-tile GEMM, BK=64, 4 waves (2x2), 64x64 acc per wave (m97 structure).
// ---------------------------------------------------------------------------
template <typename TY, int PERM>
__global__ __launch_bounds__(256) void gemm_k(
    const bf16* __restrict__ A,
    const bf16* __restrict__ W0, const bf16* __restrict__ W1, const bf16* __restrict__ W2,
    TY* __restrict__ Y0, TY* __restrict__ Y1, TY* __restrict__ Y2,
    int Kdim, float scale0)
{
  __shared__ __align__(16) bf16 As[128 * 64];
  __shared__ __align__(16) bf16 Bs[128 * 64];
  const int t = threadIdx.x, l = t & 63, w = t >> 6;
  const int wm = w >> 1, wn = w & 1;
  const int m0 = blockIdx.x * 128, n0 = blockIdx.y * 128;
  const int z = blockIdx.z;
  const bf16* W = z == 0 ? W0 : z == 1 ? W1 : W2;
  TY* Y = z == 0 ? Y0 : z == 1 ? Y1 : Y2;
  const float scale = (PERM == 1 && z == 0) ? scale0 : 1.0f;

  f32x4 acc[4][4] = {};

  for (int k0 = 0; k0 < Kdim; k0 += 64) {
    __syncthreads();
#pragma unroll
    for (int j = 0; j < 4; ++j) {
      int slot = j * 256 + t;
      int row = slot >> 3, c8 = slot & 7;
      int csw = (c8 ^ (row & 7)) << 3;
      gload16(A + (size_t)(m0 + row) * Kdim + k0 + csw, &As[(j * 256 + w * 64) * 8]);
      gload16(W + (size_t)(n0 + row) * Kdim + k0 + csw, &Bs[(j * 256 + w * 64) * 8]);
    }
    asm volatile("s_waitcnt vmcnt(0)" ::: "memory");
    __syncthreads();
#pragma unroll
    for (int kk = 0; kk < 2; ++kk) {
      bf16x8 af[4], bfr[4];
#pragma unroll
      for (int i = 0; i < 4; ++i) {
        int Ra = wm * 64 + i * 16 + (l & 15);
        int Rb = wn * 64 + i * 16 + (l & 15);
        int c = kk * 4 + (l >> 4);
        af[i] = *(const bf16x8*)&As[Ra * 64 + ((c ^ (Ra & 7)) << 3)];
        bfr[i] = *(const bf16x8*)&Bs[Rb * 64 + ((c ^ (Rb & 7)) << 3)];
      }
#pragma unroll
      for (int mi = 0; mi < 4; ++mi)
#pragma unroll
        for (int ni = 0; ni < 4; ++ni)
          acc[mi][ni] = MFMA16(af[mi], bfr[ni], acc[mi][ni]);
    }
  }

#pragma unroll
  for (int mi = 0; mi < 4; ++mi)
#pragma unroll
    for (int ni = 0; ni < 4; ++ni)
#pragma unroll
      for (int j = 0; j < 4; ++j) {
        int m = m0 + wm * 64 + mi * 16 + (l >> 4) * 4 + j;
        int n = n0 + wn * 64 + ni * 16 + (l & 15);
        float v = acc[mi][ni][j] * scale;
        if (PERM == 0) {
          Y[(size_t)m * 1024 + n] = (TY)v;
        } else {
          int b = m >> 11, s = m & (S_ - 1), h = n >> 6, d = n & (DK_ - 1);
          Y[(((size_t)(b * H_ + h)) * S_ + s) * DK_ + d] = (TY)v;
        }
      }
}

// ---------------------------------------------------------------------------
// RoPE in-place on Q and K (layout B,H,S,DK).
// ---------------------------------------------------------------------------
__global__ __launch_bounds__(256) void rope_k(
    bf16* __restrict__ Q, bf16* __restrict__ K, const int* __restrict__ pos, int npairs)
{
  int i = blockIdx.x * blockDim.x + threadIdx.x;
  bf16* buf = (i < npairs) ? Q : K;
  int idx = (i < npairs) ? i : i - npairs;
  int kp = idx & 31;
  int s = (idx >> 5) & (S_ - 1);
  int bh = idx >> 16;
  int p = pos[s];
  float inv = powf(10000.0f, -(float)kp / 32.0f);
  float ang = (float)p * inv;
  float sn, cs;
  sincosf(ang, &sn, &cs);
  size_t off = ((size_t)bh * S_ + s) * DK_ + kp * 2;
  float x0 = (float)buf[off], x1 = (float)buf[off + 1];
  buf[off] = (bf16)(x0 * cs - x1 * sn);
  buf[off + 1] = (bf16)(x0 * sn + x1 * cs);
}

// ---------------------------------------------------------------------------
// Attention helpers
// ---------------------------------------------------------------------------
__device__ __forceinline__ void qk_mfma(const bf16* Kbuf, int l, bf16x8 aq0, bf16x8 aq1,
                                        f32x4 sc4[4])
{
#pragma unroll
  for (int nf = 0; nf < 4; ++nf) {
    int R = nf * 16 + (l & 15);
    int c0 = l >> 4;
    bf16x8 b0 = *(const bf16x8*)&Kbuf[R * 64 + ((c0 ^ (R & 7)) << 3)];
    bf16x8 b1 = *(const bf16x8*)&Kbuf[R * 64 + (((4 + c0) ^ (R & 7)) << 3)];
    f32x4 s = {};
    s = MFMA16(aq0, b0, s);
    s = MFMA16(aq1, b1, s);
    sc4[nf] = s;
  }
}

__device__ __forceinline__ void diag_mask(int w, int l, f32x4 sc4[4])
{
#pragma unroll
  for (int nf = 0; nf < 4; ++nf)
#pragma unroll
    for (int j = 0; j < 4; ++j) {
      int kvl = nf * 16 + (l & 15);
      int ql = w * 16 + (l >> 4) * 4 + j;
      if (kvl > ql) sc4[nf][j] = -1e30f;
    }
}

// online-softmax + P roundtrip + PV for one 64x64 tile-update
__device__ __forceinline__ void tile_update(
    int l, const f32x4 sc4[4], f32x4 acc[4], float mrun[4], float lsum[4],
    bf16 (*Pw)[72], const bf16 (*Vc)[72])
{
  float pm[4];
#pragma unroll
  for (int j = 0; j < 4; ++j)
    pm[j] = fmaxf(fmaxf(sc4[0][j], sc4[1][j]), fmaxf(sc4[2][j], sc4[3][j]));
#pragma unroll
  for (int m = 1; m <= 8; m <<= 1)
#pragma unroll
    for (int j = 0; j < 4; ++j)
      pm[j] = fmaxf(pm[j], __shfl_xor(pm[j], m, 64));

  float alpha[4];
#pragma unroll
  for (int j = 0; j < 4; ++j) {
    float nm = fmaxf(mrun[j], pm[j]);
    alpha[j] = __expf(mrun[j] - nm);
    mrun[j] = nm;
  }

  // prior PV reads of Pw (same wave) retired before we overwrite
  asm volatile("s_waitcnt lgkmcnt(0)" ::: "memory");

  float rs[4] = {0.f, 0.f, 0.f, 0.f};
#pragma unroll
  for (int nf = 0; nf < 4; ++nf)
#pragma unroll
    for (int j = 0; j < 4; ++j) {
      float p = __expf(sc4[nf][j] - mrun[j]);
      rs[j] += p;
      Pw[(l >> 4) * 4 + j][nf * 16 + (l & 15)] = (bf16)p;
    }
#pragma unroll
  for (int m = 1; m <= 8; m <<= 1)
#pragma unroll
    for (int j = 0; j < 4; ++j)
      rs[j] += __shfl_xor(rs[j], m, 64);
#pragma unroll
  for (int j = 0; j < 4; ++j) lsum[j] = lsum[j] * alpha[j] + rs[j];
#pragma unroll
  for (int nf = 0; nf < 4; ++nf)
#pragma unroll
    for (int j = 0; j < 4; ++j)
      acc[nf][j] *= alpha[j];

  // our Ps writes visible to our reads
  asm volatile("s_waitcnt lgkmcnt(0)" ::: "memory");

  __builtin_amdgcn_s_setprio(1);
#pragma unroll
  for (int kk = 0; kk < 2; ++kk) {
    bf16x8 ap = *(const bf16x8*)&Pw[l & 15][kk * 32 + (l >> 4) * 8];
#pragma unroll
    for (int nf = 0; nf < 4; ++nf) {
      bf16x8 bv = *(const bf16x8*)&Vc[nf * 16 + (l & 15)][kk * 32 + (l >> 4) * 8];
      acc[nf] = MFMA16(ap, bv, acc[nf]);
    }
  }
  __builtin_amdgcn_s_setprio(0);
}

// ---------------------------------------------------------------------------
// Causal flash attention, paired q-tiles (qtA = 31-qtB) sharing the KV sweep.
// 4 waves x 16 q-rows per tile; double-buffered K (swizzled gload_lds) and
// V (kv-major transposed LDS). Uniform 33 tile-updates per block.
// ---------------------------------------------------------------------------
__global__ __launch_bounds__(256, 3) void attn_k(
    const bf16* __restrict__ Q, const bf16* __restrict__ K, const bf16* __restrict__ V,
    bf16* __restrict__ O)
{
  __shared__ __align__(16) bf16 Klds[2][64 * 64];
  __shared__ __align__(16) bf16 Vt[2][64][72];  // [d][kv]
  __shared__ __align__(16) bf16 Ps[4][16][72];

  const int t = threadIdx.x, l = t & 63, w = t >> 6;
  const int bh = blockIdx.x >> 4;             // 0..31
  const int qp = blockIdx.x & 15;
  const int qtB = (bh & 16) ? (15 - qp) : qp; // co-resident blocks balance staging
  const int qtA = 31 - qtB;
  const int b = bh >> 4, h = bh & 15;
  const size_t base = (size_t)bh * S_ * DK_;
  const int q0A = qtA * 64, q0B = qtB * 64;

  // Q fragments direct from global (scaled by 1/8 in the projection epilogue)
  const int qrow = w * 16 + (l & 15), qcol = (l >> 4) * 8;
  const bf16* pqA = Q + base + (size_t)(q0A + qrow) * 64 + qcol;
  const bf16* pqB = Q + base + (size_t)(q0B + qrow) * 64 + qcol;
  bf16x8 aqA0 = *(const bf16x8*)pqA, aqA1 = *(const bf16x8*)(pqA + 32);
  bf16x8 aqB0 = *(const bf16x8*)pqB, aqB1 = *(const bf16x8*)(pqB + 32);

  // prologue: stage K[0] + V[0]
  {
#pragma unroll
    for (int j = 0; j < 2; ++j) {
      int slot = j * 256 + t, row = slot >> 3, c8 = slot & 7;
      gload16(K + base + (size_t)row * 64 + ((c8 ^ (row & 7)) << 3),
              &Klds[0][(j * 256 + w * 64) * 8]);
    }
    const bf16* pv = V + base + (size_t)l * 64 + w * 16;
    bf16x8 v0 = *(const bf16x8*)pv, v1 = *(const bf16x8*)(pv + 8);
    asm volatile("s_waitcnt vmcnt(0)" ::: "memory");
#pragma unroll
    for (int i = 0; i < 8; ++i) {
      Vt[0][w * 16 + i][l] = v0[i];
      Vt[0][w * 16 + 8 + i][l] = v1[i];
    }
  }
  __syncthreads();

  f32x4 accA[4] = {}, accB[4] = {};
  float mrunA[4], lsumA[4], mrunB[4], lsumB[4];
#pragma unroll
  for (int j = 0; j < 4; ++j) {
    mrunA[j] = mrunB[j] = -1e30f;
    lsumA[j] = lsumB[j] = 0.f;
  }

  int cur = 0;
  for (int tk = 0; tk <= qtA; ++tk) {
    const int nxt = cur ^ 1;
    const bool hasn = tk < qtA;
    bf16x8 v0, v1;
    if (hasn) {  // issue next tile's loads before compute
      const int kv0n = (tk + 1) * 64;
#pragma unroll
      for (int j = 0; j < 2; ++j) {
        int slot = j * 256 + t, row = slot >> 3, c8 = slot & 7;
        gload16(K + base + (size_t)(kv0n + row) * 64 + ((c8 ^ (row & 7)) << 3),
                &Klds[nxt][(j * 256 + w * 64) * 8]);
      }
      const bf16* pv = V + base + (size_t)(kv0n + l) * 64 + w * 16;
      v0 = *(const bf16x8*)pv;
      v1 = *(const bf16x8*)(pv + 8);
    }

    const bool actB = tk <= qtB;
    f32x4 scA[4], scB[4];
    __builtin_amdgcn_s_setprio(1);
    qk_mfma(Klds[cur], l, aqA0, aqA1, scA);
    if (actB) qk_mfma(Klds[cur], l, aqB0, aqB1, scB);
    __builtin_amdgcn_s_setprio(0);
    if (tk == qtA) diag_mask(w, l, scA);
    if (tk == qtB) diag_mask(w, l, scB);

    tile_update(l, scA, accA, mrunA, lsumA, Ps[w], Vt[cur]);
    if (actB) tile_update(l, scB, accB, mrunB, lsumB, Ps[w], Vt[cur]);

    if (hasn) {  // land next V into the other buffer (conflict-free writes)
      asm volatile("s_waitcnt vmcnt(0)" ::: "memory");
#pragma unroll
      for (int i = 0; i < 8; ++i) {
        Vt[nxt][w * 16 + i][l] = v0[i];
        Vt[nxt][w * 16 + 8 + i][l] = v1[i];
      }
    }
    __syncthreads();
    cur = nxt;
  }

  // epilogue: normalize, write both tiles' O in (B,S,H*DK)
#pragma unroll
  for (int nf = 0; nf < 4; ++nf)
#pragma unroll
    for (int j = 0; j < 4; ++j) {
      int r = w * 16 + (l >> 4) * 4 + j;
      int d = nf * 16 + (l & 15);
      O[((size_t)(b * S_ + q0A + r) * H_ + h) * DK_ + d] = (bf16)(accA[nf][j] / lsumA[j]);
      O[((size_t)(b * S_ + q0B + r) * H_ + h) * DK_ + d] = (bf16)(accB[nf][j] / lsumB[j]);
    }
}

// ---------------------------------------------------------------------------
extern "C" void kernel_launch(void* const* d_in, const int* in_sizes, int n_in,
                              void* d_out, int out_size, void* d_ws, size_t ws_size,
                              hipStream_t stream)
{
  const float* x = (const float*)d_in[0];
  const float* Wq = (const float*)d_in[1];
  const float* Wk = (const float*)d_in[2];
  const float* Wv = (const float*)d_in[3];
  const float* Wo = (const float*)d_in[4];
  const int* pos = (const int*)d_in[5];

  bf16* ws = (bf16*)d_ws;
  const size_t NE = (size_t)B_ * H_ * S_ * DK_;  // 4,194,304
  bf16* xb = ws;
  bf16* Wqb = ws + NE;
  bf16* Wkb = Wqb + 1048576;
  bf16* Wvb = Wkb + 1048576;
  bf16* Wob = Wvb + 1048576;
  bf16* Qb = Wob + 1048576;
  bf16* Kb = Qb + NE;
  bf16* Vb = Kb + NE;
  bf16* Ob = xb;  // x dead after QKV projections

  dim3 blk(256);

  hipLaunchKernelGGL(cvt_k, dim3(8192), blk, 0, stream, x, Wq, Wk, Wv, Wo, ws);

  hipLaunchKernelGGL((gemm_k<bf16, 1>), dim3(32, 8, 3), blk, 0, stream,
                     xb, Wqb, Wkb, Wvb, Qb, Kb, Vb, 1024, 0.125f);

  int npairs = B_ * H_ * S_ * (DK_ / 2);
  hipLaunchKernelGGL(rope_k, dim3((2 * npairs) / 256), blk, 0, stream, Qb, Kb, pos, npairs);

  // paired-tile causal flash attention -> Ob (B,S,H*DK)
  hipLaunchKernelGGL(attn_k, dim3(32 * 16), blk, 0, stream, Qb, Kb, Vb, Ob);

  hipLaunchKernelGGL((gemm_k<float, 0>), dim3(32, 8, 1), blk, 0, stream,
                     Ob, Wob, Wob, Wob, (float*)d_out, (float*)d_out, (float*)d_out,
                     1024, 1.0f);
}